// Round 6
// baseline (47.864 us; speedup 1.0000x reference)
//
#include <hip/hip_runtime.h>
#include <math.h>

#define TT 512
#define KP 4

typedef unsigned long long u64;

// 512 blocks x 512 threads (8 waves). Each block: 4 rows (b, n0..n0+3) in 4
// supersteps; the store of row s-1 is ISSUED at the top of superstep s and
// drains under superstep s's compute. 2 blocks/CU = 16 waves/CU.
__global__ __launch_bounds__(512) void periodicity_kernel(const float* __restrict__ x,
                                                          float* __restrict__ out) {
    const int blk  = blockIdx.x;     // 0..511
    const int tid  = threadIdx.x;    // 0..511
    const int lane = tid & 63;
    const int wid  = tid >> 6;
    const int b  = blk >> 4;         // 0..31
    const int n0 = (blk & 15) << 2;  // 0,4,...,60

    __shared__ float2 tw[TT];                       // tw[m] = e^{-2*pi*i*m/512}
    __shared__ __align__(16) float rowl[2][TT];     // double-buffered natural-order row
    __shared__ float2 buf[TT];                      // FFT working buffer
    __shared__ u64    keys[256];
    __shared__ int    fin8[8];
    __shared__ double candV8[8];
    __shared__ int    pstore[2][12];                // per[4], cyc[4], st[4] (double-buffered)

    // twiddles: one sincosf per thread fills all 512 entries
    {
        float s, c;
        sincosf((float)(2.0 * M_PI / 512.0) * (float)tid, &s, &c);
        tw[tid] = make_float2(c, -s);
    }

    // prefetch all 4 rows: thread tid holds x[b, tid, n0..n0+3]
    const float* xb = x + (size_t)b * (TT * 64) + n0;
    float4 ld = *(const float4*)(xb + (size_t)tid * 64);

    const size_t VOFF = (size_t)2048 * KP * 64 * 64;   // 33,554,432

    // gather + store one row's 64KB values region from rowl[pvb]/pstore[pvb]
    auto store_row = [&](int rowIdx, int pvb) {
        const int bnp = b * 64 + n0 + rowIdx;
        float* outv = out + (size_t)bnp * (KP * 64 * 64);
        #pragma unroll
        for (int it = 0; it < 8; ++it) {
            const int flat4 = it * 512 + tid;       // 0..4095
            const int k   = flat4 >> 10;
            const int rem = flat4 & 1023;
            const int c   = rem >> 4;
            const int p0  = (rem & 15) << 2;
            const int P = pstore[pvb][k], C = pstore[pvb][4 + k], S0 = pstore[pvb][8 + k];
            float4 v = make_float4(0.f, 0.f, 0.f, 0.f);
            if (c < C) {
                const int base = S0 + c * P;
                if (p0 + 3 < P) {
                    v.x = rowl[pvb][base + p0];
                    v.y = rowl[pvb][base + p0 + 1];
                    v.z = rowl[pvb][base + p0 + 2];
                    v.w = rowl[pvb][base + p0 + 3];
                } else {
                    if (p0     < P) v.x = rowl[pvb][base + p0];
                    if (p0 + 1 < P) v.y = rowl[pvb][base + p0 + 1];
                    if (p0 + 2 < P) v.z = rowl[pvb][base + p0 + 2];
                    if (p0 + 3 < P) v.w = rowl[pvb][base + p0 + 3];
                }
            }
            *(float4*)(outv + (size_t)flat4 * 4) = v;
        }
    };

    #pragma unroll
    for (int ss = 0; ss < 4; ++ss) {
        const int cur = ss & 1, pv = cur ^ 1;

        // ---- issue stores of row ss-1 (reads rowl[pv]/pstore[pv]; drains async) ----
        if (ss > 0) store_row(ss - 1, pv);

        // ---- stage current row into rowl[cur] (disjoint from rowl[pv]) ----
        {
            float rv = (ss == 0) ? ld.x : (ss == 1) ? ld.y : (ss == 2) ? ld.z : ld.w;
            rowl[cur][tid] = rv;
        }
        __syncthreads();

        // ---- folded radix-2 first DIF stage (all 512 threads, one output each) ----
        if (tid < 256) {
            buf[tid] = make_float2(rowl[cur][tid] + rowl[cur][tid + 256], 0.f);
        } else {
            const int j = tid - 256;
            float dif = rowl[cur][j] - rowl[cur][j + 256];
            float2 t = tw[j];
            buf[tid] = make_float2(dif * t.x, dif * t.y);
        }
        __syncthreads();

        // ---- 4 radix-4 DIF stages on the two 256-halves (128 active threads) ----
        #pragma unroll
        for (int stg = 0; stg < 4; ++stg) {
            if (tid < 128) {
                const int Q  = 64 >> (2 * stg);          // 64,16,4,1
                const int B4 = Q << 2;
                const int h  = tid >> 6;
                const int fj = tid & 63;
                const int g  = fj >> (6 - 2 * stg);
                const int i  = fj & (Q - 1);
                float2* bb = &buf[h << 8];
                const int base = g * B4 + i;
                float2 x0 = bb[base],         x1 = bb[base + Q];
                float2 x2 = bb[base + 2 * Q], x3 = bb[base + 3 * Q];
                float2 A  = make_float2(x0.x + x2.x, x0.y + x2.y);
                float2 Bm = make_float2(x0.x - x2.x, x0.y - x2.y);
                float2 Cc = make_float2(x1.x + x3.x, x1.y + x3.y);
                float2 D  = make_float2(x1.x - x3.x, x1.y - x3.y);
                float2 y0 = make_float2(A.x + Cc.x, A.y + Cc.y);
                float2 y2 = make_float2(A.x - Cc.x, A.y - Cc.y);
                float2 y1 = make_float2(Bm.x + D.y, Bm.y - D.x);   // Bm - i*D
                float2 y3 = make_float2(Bm.x - D.y, Bm.y + D.x);   // Bm + i*D
                const int m = i << (1 + 2 * stg);
                float2 t1 = tw[m], t2 = tw[2 * m], t3 = tw[3 * m];
                bb[base]         = y0;
                bb[base + Q]     = make_float2(y1.x * t1.x - y1.y * t1.y, y1.x * t1.y + y1.y * t1.x);
                bb[base + 2 * Q] = make_float2(y2.x * t2.x - y2.y * t2.y, y2.x * t2.y + y2.y * t2.x);
                bb[base + 3 * Q] = make_float2(y3.x * t3.x - y3.y * t3.y, y3.x * t3.y + y3.y * t3.x);
            }
            __syncthreads();
        }

        // ---- scatter |X|^2 into packed keys (base-4 digit-reversed order) ----
        {
            const int p  = tid & 255;
            const int hh = tid >> 8;
            const int kp = ((p & 3) << 6) | (((p >> 2) & 3) << 4) | (((p >> 4) & 3) << 2) | ((p >> 6) & 3);
            const int f = 2 * kp + hh;
            if (f >= 1 && f <= 256) {
                float2 v = buf[tid];
                float mag = v.x * v.x + v.y * v.y;
                keys[f - 1] = ((u64)__float_as_uint(mag) << 32) | (u64)(255 - (f - 1));
            }
        }
        __syncthreads();

        // ---- top-8 of 256 keys (wave 0; value desc, bin asc) ----
        if (wid == 0) {
            u64 k0 = keys[lane * 4 + 0];
            u64 k1 = keys[lane * 4 + 1];
            u64 k2 = keys[lane * 4 + 2];
            u64 k3 = keys[lane * 4 + 3];
            #define CSWAP(a, b) { if (a < b) { u64 _t = a; a = b; b = _t; } }
            CSWAP(k0, k1) CSWAP(k2, k3) CSWAP(k0, k2) CSWAP(k1, k3) CSWAP(k1, k2)
            #undef CSWAP
            #pragma unroll
            for (int r = 0; r < 8; ++r) {
                u64 w = k0;
                #pragma unroll
                for (int off = 32; off >= 1; off >>= 1) {
                    u64 o = __shfl_xor(w, off);
                    if (o > w) w = o;
                }
                if (k0 == w) { k0 = k1; k1 = k2; k2 = k3; k3 = 0; }
                if (lane == 0) fin8[r] = 256 - (int)(w & 0xff);
            }
        }
        __syncthreads();

        // ---- f64 refine of the 8 candidates (tid<256: 8 cand x 32 threads) ----
        if (tid < 256) {
            const int cid = tid >> 5;
            const int sub = tid & 31;
            const int fc  = fin8[cid];
            const int t0  = sub * 16;
            const double W = 6.2831853071795864769 / 512.0;
            double zr, zi, wr, wi;
            sincos(W * (double)((fc * t0) & 511), &zi, &zr);
            sincos(W * (double)fc, &wi, &wr);
            double ar = 0.0, ai = 0.0;
            const float4* r4 = (const float4*)rowl[cur];
            #pragma unroll
            for (int v4i = 0; v4i < 4; ++v4i) {
                float4 xv = r4[sub * 4 + v4i];
                #define STEP(comp)                                   \
                    { double xd = (double)xv.comp;                   \
                      ar = fma(xd, zr, ar); ai = fma(xd, zi, ai);    \
                      double tq = zr * wr - zi * wi;                 \
                      zi = fma(zr, wi, zi * wr); zr = tq; }
                STEP(x) STEP(y) STEP(z) STEP(w)
                #undef STEP
            }
            #pragma unroll
            for (int off = 16; off >= 1; off >>= 1) {
                ar += __shfl_xor(ar, off);
                ai += __shfl_xor(ai, off);
            }
            if (sub == 0) candV8[cid] = ar * ar + ai * ai;
        }
        __syncthreads();

        // ---- final top-4 + params (wave 0 computes; tid 0 publishes) ----
        if (wid == 0) {
            int per[KP], cycv[KP], stv[KP];
            unsigned chosen = 0;
            #pragma unroll
            for (int k = 0; k < KP; ++k) {
                double bv = -1.0; int bbin = 0x7fffffff; int bj = 0;
                #pragma unroll
                for (int j = 0; j < 8; ++j) {
                    if (chosen & (1u << j)) continue;
                    double vj = candV8[j];
                    int    bjn = fin8[j];
                    if (vj > bv || (vj == bv && bjn < bbin)) { bv = vj; bbin = bjn; bj = j; }
                }
                chosen |= (1u << bj);
                int p = TT / bbin;
                p = p < 8 ? 8 : (p > 64 ? 64 : p);
                per[k]  = p;
                cycv[k] = TT / p;
                stv[k]  = TT - cycv[k] * p;
            }
            if (lane == 0) {
                const int bn = b * 64 + n0 + ss;
                #pragma unroll
                for (int k = 0; k < KP; ++k) {
                    pstore[cur][k]     = per[k];
                    pstore[cur][4 + k] = cycv[k];
                    pstore[cur][8 + k] = stv[k];
                    out[VOFF + (size_t)bn * KP + k]        = (float)per[k];
                    out[VOFF + 8192 + (size_t)bn * KP + k] = (float)cycv[k];
                }
            }
        }
        __syncthreads();   // pstore[cur]/rowl[cur] ready for next superstep's store
    }

    // ---- drain: store row 3 (buffer parity 1) ----
    store_row(3, 1);
}

extern "C" void kernel_launch(void* const* d_in, const int* in_sizes, int n_in,
                              void* d_out, int out_size, void* d_ws, size_t ws_size,
                              hipStream_t stream) {
    const float* x = (const float*)d_in[0];
    float* out = (float*)d_out;
    hipLaunchKernelGGL(periodicity_kernel, dim3(512), dim3(512), 0, stream, x, out);
}

// Round 7
// 35.751 us; speedup vs baseline: 1.3388x; 1.3388x over previous
//
#include <hip/hip_runtime.h>
#include <math.h>

#define TT 512
#define KP 4

typedef unsigned long long u64;

// LDS-only barrier: waits DS ops, leaves global stores in flight (T4 pattern).
#define SYNCL() asm volatile("s_waitcnt lgkmcnt(0)\n\ts_barrier" ::: "memory")

// one block per sequence row (bn = b*64 + n). 256 threads = 4 waves.
__global__ __launch_bounds__(256) void periodicity_kernel(const float* __restrict__ x,
                                                          float* __restrict__ out) {
    const int bn   = blockIdx.x;     // 0..2047
    const int tid  = threadIdx.x;    // 0..255
    const int lane = tid & 63;
    const int wid  = tid >> 6;
    const int b = bn >> 6;
    const int n = bn & 63;

    __shared__ float2 tw[TT];                       // tw[m] = e^{-2*pi*i*m/512}
    __shared__ __align__(16) float row[TT];         // natural order
    __shared__ float2 buf[TT];                      // FFT working buffer
    __shared__ u64    keys[256];                    // (mag_bits<<32)|(255-(f-1))
    __shared__ int    fin8[8];
    __shared__ float  candMagF[8];
    __shared__ double candV8[8];
    __shared__ unsigned char w4tab[64];             // W4(c): float4-cols of possible-nonzero

    // ---- twiddles (one sincosf/thread) + W4 table ----
    float sv, cv;
    sincosf((float)(2.0 * M_PI / 512.0) * (float)tid, &sv, &cv);
    tw[tid]       = make_float2(cv, -sv);
    tw[tid + 256] = make_float2(-cv, sv);
    if (tid < 64) {
        int W = 512 / (tid + 1);
        W = W < 8 ? 8 : (W > 64 ? 64 : W);
        w4tab[tid] = (unsigned char)((W + 3) >> 2);
    }

    // ---- load row (stride-64 column) + folded radix-2 first DIF stage ----
    const float* xb = x + (size_t)b * (TT * 64) + n;
    {
        float v0 = xb[(size_t)tid * 64];
        float v1 = xb[(size_t)(tid + 256) * 64];
        row[tid] = v0;  row[tid + 256] = v1;
        float sum = v0 + v1, dif = v0 - v1;
        buf[tid]       = make_float2(sum, 0.f);
        buf[tid + 256] = make_float2(dif * cv, -dif * sv);
    }
    SYNCL();

    // ---- pass-1: zero-store the universally-zero region (drains under compute) ----
    float* outv = out + (size_t)bn * (KP * 64 * 64);
    {
        const int j  = tid & 15;      // float4 column
        const int cb = tid >> 4;      // row offset within group of 16
        #pragma unroll
        for (int iter = 0; iter < 4; ++iter) {
            const int c = 8 + iter * 16 + cb;     // rows 0..7 are never universally zero
            if (c < 64 && j >= (int)w4tab[c]) {
                const float4 z = make_float4(0.f, 0.f, 0.f, 0.f);
                #pragma unroll
                for (int k = 0; k < KP; ++k)
                    *(float4*)(outv + k * 4096 + c * 64 + j * 4) = z;
            }
        }
    }

    // ---- 4 radix-4 DIF stages on the two 256-halves (128 active threads) ----
    #pragma unroll
    for (int stg = 0; stg < 4; ++stg) {
        if (tid < 128) {
            const int Q  = 64 >> (2 * stg);          // 64,16,4,1
            const int B4 = Q << 2;
            const int h  = tid >> 6;
            const int fj = tid & 63;
            const int g  = fj >> (6 - 2 * stg);
            const int i  = fj & (Q - 1);
            float2* bb = &buf[h << 8];
            const int base = g * B4 + i;
            float2 x0 = bb[base],         x1 = bb[base + Q];
            float2 x2 = bb[base + 2 * Q], x3 = bb[base + 3 * Q];
            float2 A  = make_float2(x0.x + x2.x, x0.y + x2.y);
            float2 Bm = make_float2(x0.x - x2.x, x0.y - x2.y);
            float2 Cc = make_float2(x1.x + x3.x, x1.y + x3.y);
            float2 D  = make_float2(x1.x - x3.x, x1.y - x3.y);
            float2 y0 = make_float2(A.x + Cc.x, A.y + Cc.y);
            float2 y2 = make_float2(A.x - Cc.x, A.y - Cc.y);
            float2 y1 = make_float2(Bm.x + D.y, Bm.y - D.x);   // Bm - i*D
            float2 y3 = make_float2(Bm.x - D.y, Bm.y + D.x);   // Bm + i*D
            const int m = i << (1 + 2 * stg);
            float2 t1 = tw[m], t2 = tw[2 * m], t3 = tw[3 * m];
            bb[base]         = y0;
            bb[base + Q]     = make_float2(y1.x * t1.x - y1.y * t1.y, y1.x * t1.y + y1.y * t1.x);
            bb[base + 2 * Q] = make_float2(y2.x * t2.x - y2.y * t2.y, y2.x * t2.y + y2.y * t2.x);
            bb[base + 3 * Q] = make_float2(y3.x * t3.x - y3.y * t3.y, y3.x * t3.y + y3.y * t3.x);
        }
        SYNCL();
    }

    // ---- scatter |X|^2 into packed keys (base-4 digit-reversed order) ----
    #pragma unroll
    for (int hh = 0; hh < 2; ++hh) {
        const int p = tid;
        const int kp = ((p & 3) << 6) | (((p >> 2) & 3) << 4) | (((p >> 4) & 3) << 2) | ((p >> 6) & 3);
        const int f = 2 * kp + hh;
        if (f >= 1 && f <= 256) {
            float2 v = buf[hh * 256 + p];
            float mag = v.x * v.x + v.y * v.y;
            keys[f - 1] = ((u64)__float_as_uint(mag) << 32) | (u64)(255 - (f - 1));
        }
    }
    SYNCL();

    // ---- top-8 of 256 keys (wave 0; value desc, bin asc) ----
    if (wid == 0) {
        u64 k0 = keys[lane * 4 + 0];
        u64 k1 = keys[lane * 4 + 1];
        u64 k2 = keys[lane * 4 + 2];
        u64 k3 = keys[lane * 4 + 3];
        #define CSWAP(a, b) { if (a < b) { u64 _t = a; a = b; b = _t; } }
        CSWAP(k0, k1) CSWAP(k2, k3) CSWAP(k0, k2) CSWAP(k1, k3) CSWAP(k1, k2)
        #undef CSWAP
        #pragma unroll
        for (int r = 0; r < 8; ++r) {
            u64 w = k0;
            #pragma unroll
            for (int off = 32; off >= 1; off >>= 1) {
                u64 o = __shfl_xor(w, off);
                if (o > w) w = o;
            }
            if (k0 == w) { k0 = k1; k1 = k2; k2 = k3; k3 = 0; }
            if (lane == 0) {
                fin8[r] = 256 - (int)(w & 0xff);
                candMagF[r] = __uint_as_float((unsigned)(w >> 32));
            }
        }
    }
    SYNCL();

    // ---- gap check: is the fp32 ranking provably exact? (uniform branch) ----
    int per[KP], cycv[KP], stv[KP];
    {
        const float m0 = candMagF[0], m1 = candMagF[1], m2 = candMagF[2],
                    m3 = candMagF[3], m4 = candMagF[4];
        const bool needRefine = ((m0 - m1) <= 1e-4f * m0) || ((m1 - m2) <= 1e-4f * m1) ||
                                ((m2 - m3) <= 1e-4f * m2) || ((m3 - m4) <= 1e-4f * m3);
        int bins[KP];
        if (!needRefine) {
            #pragma unroll
            for (int k = 0; k < KP; ++k) bins[k] = fin8[k];
        } else {
            // ---- f64 refine of the 8 candidates (rare; exact ranking) ----
            {
                const int cid = tid >> 5;
                const int sub = tid & 31;
                const int fc  = fin8[cid];
                const int t0  = sub * 16;
                const double W = 6.2831853071795864769 / 512.0;
                double zr, zi, wr, wi;
                sincos(W * (double)((fc * t0) & 511), &zi, &zr);
                sincos(W * (double)fc, &wi, &wr);
                double ar = 0.0, ai = 0.0;
                const float4* r4 = (const float4*)row;
                #pragma unroll
                for (int v4i = 0; v4i < 4; ++v4i) {
                    float4 xv = r4[sub * 4 + v4i];
                    #define STEP(comp)                                   \
                        { double xd = (double)xv.comp;                   \
                          ar = fma(xd, zr, ar); ai = fma(xd, zi, ai);    \
                          double tq = zr * wr - zi * wi;                 \
                          zi = fma(zr, wi, zi * wr); zr = tq; }
                    STEP(x) STEP(y) STEP(z) STEP(w)
                    #undef STEP
                }
                #pragma unroll
                for (int off = 16; off >= 1; off >>= 1) {
                    ar += __shfl_xor(ar, off);
                    ai += __shfl_xor(ai, off);
                }
                if (sub == 0) candV8[cid] = ar * ar + ai * ai;
            }
            SYNCL();
            unsigned chosen = 0;
            #pragma unroll
            for (int k = 0; k < KP; ++k) {
                double bv = -1.0; int bbin = 0x7fffffff; int bj = 0;
                #pragma unroll
                for (int j = 0; j < 8; ++j) {
                    if (chosen & (1u << j)) continue;
                    double vj = candV8[j];
                    int    bjn = fin8[j];
                    if (vj > bv || (vj == bv && bjn < bbin)) { bv = vj; bbin = bjn; bj = j; }
                }
                chosen |= (1u << bj);
                bins[k] = bbin;
            }
        }
        #pragma unroll
        for (int k = 0; k < KP; ++k) {
            int p = TT / bins[k];
            p = p < 8 ? 8 : (p > 64 ? 64 : p);
            per[k]  = p;
            cycv[k] = TT / p;
            stv[k]  = TT - cycv[k] * p;
        }
    }

    const size_t VOFF = (size_t)2048 * KP * 64 * 64;   // 33,554,432
    if (tid == 0) {
        #pragma unroll
        for (int k = 0; k < KP; ++k) {
            out[VOFF + (size_t)bn * KP + k]        = (float)per[k];
            out[VOFF + 8192 + (size_t)bn * KP + k] = (float)cycv[k];
        }
    }

    // ---- pass-2: write the possible-nonzero region (j < W4(c)) with data/zeros ----
    {
        const int c  = tid >> 2;          // 0..63
        const int j0 = tid & 3;
        const int W4c = (int)w4tab[c];
        #pragma unroll
        for (int k = 0; k < KP; ++k) {
            const int P = per[k], C = cycv[k], S0 = stv[k];
            const int inC  = (c < C) ? 1 : 0;
            const int base = S0 + c * P;
            #pragma unroll
            for (int m = 0; m < 4; ++m) {
                const int j = j0 + (m << 2);
                if (j < W4c) {
                    const int p0 = j << 2;
                    float4 v = make_float4(0.f, 0.f, 0.f, 0.f);
                    if (inC) {
                        if (p0     < P) v.x = row[base + p0];
                        if (p0 + 1 < P) v.y = row[base + p0 + 1];
                        if (p0 + 2 < P) v.z = row[base + p0 + 2];
                        if (p0 + 3 < P) v.w = row[base + p0 + 3];
                    }
                    *(float4*)(outv + k * 4096 + c * 64 + p0) = v;
                }
            }
        }
    }
}

extern "C" void kernel_launch(void* const* d_in, const int* in_sizes, int n_in,
                              void* d_out, int out_size, void* d_ws, size_t ws_size,
                              hipStream_t stream) {
    const float* x = (const float*)d_in[0];
    float* out = (float*)d_out;
    hipLaunchKernelGGL(periodicity_kernel, dim3(2048), dim3(256), 0, stream, x, out);
}